// Round 1
// 360.100 us; speedup vs baseline: 1.2047x; 1.2047x over previous
//
#include <hip/hip_runtime.h>
#include <stdint.h>

#define NUM_LEVELS 16
#define LEVEL_DIM 2
#define BASE_RES 16
#define LOG2_T 19
#define TABLE_SIZE (1u << LOG2_T)
#define TABLE_MASK (TABLE_SIZE - 1u)
#define PAIR_MASK (TABLE_MASK & ~1u)   /* 0x7FFFE: 16B-aligned entry pair */

#define CPL 256      // chunk-blocks per level (8*CPL = 2048 = resident-block capacity)
#define BLOCK 256

typedef float v2f __attribute__((ext_vector_type(2)));
typedef float v4f __attribute__((ext_vector_type(4)));

// ---------------- Phase 1: level-sharded gather ----------------
// blockIdx % 8 -> XCD (dispatch round-robin). Levels 0..7 run first
// (blocks 0..2047), then 8..15; each XCD's 4MB L2 holds exactly one table.
//
// Hash-pair trick: hash = ix ^ iy*P2 ^ iz*P3 ^ lv. For EVEN ix,
// hash(ix+1) = hash(ix) ^ 1, so both x-corners sit in the same 16B-aligned
// entry pair -> one dwordx4 load covers two corners (4 line-requests/point
// instead of 8). Odd ix falls back to 8x dwordx2. Avg 6 requests/point.
//
// x loads are PLAIN (not nontemporal): x (6 MiB) is re-read once per level
// per XCD; cached loads let L3 serve the re-reads instead of HBM.
__global__ __launch_bounds__(256, 6) void gather_level_kernel(
    const float* __restrict__ x,
    const float* __restrict__ tables,
    float* __restrict__ ws,      // [NUM_LEVELS][N] float2, level-major
    int N)
{
    int g = blockIdx.x;
    int half  = g / (8 * CPL);          // 0 or 1
    int h     = g % (8 * CPL);
    int level = (h & 7) + 8 * half;
    int chunk = h >> 3;
    int P     = (N + CPL - 1) / CPL;    // points per chunk
    int base  = chunk * P;

    const float* tb = tables + (size_t)level * TABLE_SIZE * LEVEL_DIM;
    const v4f*   tp = (const v4f*)tb;   // entry pairs, 16B each
    v2f* wrow = (v2f*)ws + (size_t)level * N;
    float res = (float)(BASE_RES << level);
    uint32_t lv = (uint32_t)level;

    for (int i = threadIdx.x; i < P; i += BLOCK) {
        int n = base + i;
        if (n >= N) break;

        float px = x[(size_t)n * 3 + 0];
        float py = x[(size_t)n * 3 + 1];
        float pz = x[(size_t)n * 3 + 2];

        px = fminf(fmaxf((px + 1.0f) * 0.5f, 0.0f), 1.0f - 1e-6f);
        py = fminf(fmaxf((py + 1.0f) * 0.5f, 0.0f), 1.0f - 1e-6f);
        pz = fminf(fmaxf((pz + 1.0f) * 0.5f, 0.0f), 1.0f - 1e-6f);

        float sx = px * res, sy = py * res, sz = pz * res;
        float fx = floorf(sx), fy = floorf(sy), fz = floorf(sz);
        float tx = sx - fx, ty = sy - fy, tz = sz - fz;
        uint32_t ix = (uint32_t)(int32_t)fx;
        uint32_t iy = (uint32_t)(int32_t)fy;
        uint32_t iz = (uint32_t)(int32_t)fz;

        uint32_t hy0 = iy * 2654435761u;
        uint32_t hy1 = (iy + 1u) * 2654435761u;
        uint32_t hz0 = iz * 805459861u;
        uint32_t hz1 = (iz + 1u) * 805459861u;
        uint32_t m00 = hy0 ^ hz0 ^ lv;
        uint32_t m01 = hy0 ^ hz1 ^ lv;
        uint32_t m10 = hy1 ^ hz0 ^ lv;
        uint32_t m11 = hy1 ^ hz1 ^ lv;

        float wx1 = tx, wx0 = 1.0f - tx;
        float wy1 = ty, wy0 = 1.0f - ty;
        float wz1 = tz, wz0 = 1.0f - tz;
        float w00 = wy0 * wz0, w01 = wy0 * wz1;
        float w10 = wy1 * wz0, w11 = wy1 * wz1;

        // a = corner x=ix (weight wx0), b = corner x=ix+1 (weight wx1),
        // each already summed over the 4 (y,z) corners.
        float ax, ay, bx, by;

        if ((ix & 1u) == 0u) {
            // even ix: hash(ix+1) == hash(ix)^1 -> shared 16B pair
            uint32_t h00 = ix ^ m00, h01 = ix ^ m01;
            uint32_t h10 = ix ^ m10, h11 = ix ^ m11;
            v4f p00 = tp[(h00 & PAIR_MASK) >> 1];
            v4f p01 = tp[(h01 & PAIR_MASK) >> 1];
            v4f p10 = tp[(h10 & PAIR_MASK) >> 1];
            v4f p11 = tp[(h11 & PAIR_MASK) >> 1];
            // bit0 of hash selects which 8B half is corner ix; other half is ix+1
            bool s00 = (h00 & 1u), s01 = (h01 & 1u);
            bool s10 = (h10 & 1u), s11 = (h11 & 1u);
            float a00x = s00 ? p00.z : p00.x, a00y = s00 ? p00.w : p00.y;
            float b00x = s00 ? p00.x : p00.z, b00y = s00 ? p00.y : p00.w;
            float a01x = s01 ? p01.z : p01.x, a01y = s01 ? p01.w : p01.y;
            float b01x = s01 ? p01.x : p01.z, b01y = s01 ? p01.y : p01.w;
            float a10x = s10 ? p10.z : p10.x, a10y = s10 ? p10.w : p10.y;
            float b10x = s10 ? p10.x : p10.z, b10y = s10 ? p10.y : p10.w;
            float a11x = s11 ? p11.z : p11.x, a11y = s11 ? p11.w : p11.y;
            float b11x = s11 ? p11.x : p11.z, b11y = s11 ? p11.y : p11.w;
            ax = a00x * w00 + a01x * w01 + a10x * w10 + a11x * w11;
            ay = a00y * w00 + a01y * w01 + a10y * w10 + a11y * w11;
            bx = b00x * w00 + b01x * w01 + b10x * w10 + b11x * w11;
            by = b00y * w00 + b01y * w01 + b10y * w10 + b11y * w11;
        } else {
            uint32_t ja = ix, jb = ix + 1u;
            v2f e00a = *(const v2f*)(tb + (size_t)(((ja ^ m00) & TABLE_MASK) * 2u));
            v2f e01a = *(const v2f*)(tb + (size_t)(((ja ^ m01) & TABLE_MASK) * 2u));
            v2f e10a = *(const v2f*)(tb + (size_t)(((ja ^ m10) & TABLE_MASK) * 2u));
            v2f e11a = *(const v2f*)(tb + (size_t)(((ja ^ m11) & TABLE_MASK) * 2u));
            v2f e00b = *(const v2f*)(tb + (size_t)(((jb ^ m00) & TABLE_MASK) * 2u));
            v2f e01b = *(const v2f*)(tb + (size_t)(((jb ^ m01) & TABLE_MASK) * 2u));
            v2f e10b = *(const v2f*)(tb + (size_t)(((jb ^ m10) & TABLE_MASK) * 2u));
            v2f e11b = *(const v2f*)(tb + (size_t)(((jb ^ m11) & TABLE_MASK) * 2u));
            ax = e00a.x * w00 + e01a.x * w01 + e10a.x * w10 + e11a.x * w11;
            ay = e00a.y * w00 + e01a.y * w01 + e10a.y * w10 + e11a.y * w11;
            bx = e00b.x * w00 + e01b.x * w01 + e10b.x * w10 + e11b.x * w11;
            by = e00b.y * w00 + e01b.y * w01 + e10b.y * w10 + e11b.y * w11;
        }

        v2f acc;
        acc.x = ax * wx0 + bx * wx1;
        acc.y = ay * wx0 + by * wx1;
        __builtin_nontemporal_store(acc, wrow + n);
    }
}

// ---------------- Phase 2: [L][N][2] -> [N][L*2] transpose ----------------
// Lane remap for coalesced stores: thread t owns 16B chunk c = t&7 of point
// p = t>>3 (levels 2c, 2c+1). Reads: for each load, the 8 lanes with equal
// (t&7) read 8 consecutive points of one level = one full 64B line -> fully
// coalesced. Stores: lane i writes 16B at out + t*16 -> contiguous 1KB per
// wave, full lines per instruction -> NT store safe, no partial-line RMW or
// request amplification (the old per-point v4f stores were 64-lane scatters
// at 128B stride: 4x write-request amplification, ~1.1 TB/s).
__global__ __launch_bounds__(256) void transpose_kernel(
    const float* __restrict__ ws, float* __restrict__ out, int N)
{
    int t = blockIdx.x * blockDim.x + threadIdx.x;
    int p = t >> 3;
    if (p >= N) return;
    int c = t & 7;

    v2f a = __builtin_nontemporal_load((const v2f*)ws + (size_t)(2 * c)     * N + p);
    v2f b = __builtin_nontemporal_load((const v2f*)ws + (size_t)(2 * c + 1) * N + p);
    v4f o;
    o.x = a.x; o.y = a.y; o.z = b.x; o.w = b.y;
    __builtin_nontemporal_store(o, (v4f*)out + (size_t)t);
}

// ---------------- Fallback: point-major (round-1 kernel, passing) ----------
__device__ __forceinline__ v2f encode_point(
    const float* __restrict__ x, const float* __restrict__ tb,
    int n, float res, uint32_t lv)
{
    float px = x[(size_t)n * 3 + 0];
    float py = x[(size_t)n * 3 + 1];
    float pz = x[(size_t)n * 3 + 2];

    px = fminf(fmaxf((px + 1.0f) * 0.5f, 0.0f), 1.0f - 1e-6f);
    py = fminf(fmaxf((py + 1.0f) * 0.5f, 0.0f), 1.0f - 1e-6f);
    pz = fminf(fmaxf((pz + 1.0f) * 0.5f, 0.0f), 1.0f - 1e-6f);

    float sx = px * res, sy = py * res, sz = pz * res;
    float fx = floorf(sx), fy = floorf(sy), fz = floorf(sz);
    float tx = sx - fx, ty = sy - fy, tz = sz - fz;
    uint32_t ix = (uint32_t)(int32_t)fx;
    uint32_t iy = (uint32_t)(int32_t)fy;
    uint32_t iz = (uint32_t)(int32_t)fz;

    uint32_t hx0 = ix, hx1 = ix + 1u;
    uint32_t hy0 = iy * 2654435761u, hy1 = (iy + 1u) * 2654435761u;
    uint32_t hz0 = iz * 805459861u,  hz1 = (iz + 1u) * 805459861u;

    uint32_t idx0 = ((hx0 ^ hy0 ^ hz0 ^ lv) & TABLE_MASK) * 2u;
    uint32_t idx1 = ((hx0 ^ hy0 ^ hz1 ^ lv) & TABLE_MASK) * 2u;
    uint32_t idx2 = ((hx0 ^ hy1 ^ hz0 ^ lv) & TABLE_MASK) * 2u;
    uint32_t idx3 = ((hx0 ^ hy1 ^ hz1 ^ lv) & TABLE_MASK) * 2u;
    uint32_t idx4 = ((hx1 ^ hy0 ^ hz0 ^ lv) & TABLE_MASK) * 2u;
    uint32_t idx5 = ((hx1 ^ hy0 ^ hz1 ^ lv) & TABLE_MASK) * 2u;
    uint32_t idx6 = ((hx1 ^ hy1 ^ hz0 ^ lv) & TABLE_MASK) * 2u;
    uint32_t idx7 = ((hx1 ^ hy1 ^ hz1 ^ lv) & TABLE_MASK) * 2u;

    v2f e0 = *(const v2f*)(tb + idx0);
    v2f e1 = *(const v2f*)(tb + idx1);
    v2f e2 = *(const v2f*)(tb + idx2);
    v2f e3 = *(const v2f*)(tb + idx3);
    v2f e4 = *(const v2f*)(tb + idx4);
    v2f e5 = *(const v2f*)(tb + idx5);
    v2f e6 = *(const v2f*)(tb + idx6);
    v2f e7 = *(const v2f*)(tb + idx7);

    float wx0 = 1.0f - tx, wx1 = tx;
    float wy0 = 1.0f - ty, wy1 = ty;
    float wz0 = 1.0f - tz, wz1 = tz;

    float w0 = wx0 * wy0 * wz0;
    float w1 = wx0 * wy0 * wz1;
    float w2 = wx0 * wy1 * wz0;
    float w3 = wx0 * wy1 * wz1;
    float w4 = wx1 * wy0 * wz0;
    float w5 = wx1 * wy0 * wz1;
    float w6 = wx1 * wy1 * wz0;
    float w7 = wx1 * wy1 * wz1;

    v2f acc;
    acc.x = e0.x * w0 + e1.x * w1 + e2.x * w2 + e3.x * w3
          + e4.x * w4 + e5.x * w5 + e6.x * w6 + e7.x * w7;
    acc.y = e0.y * w0 + e1.y * w1 + e2.y * w2 + e3.y * w3
          + e4.y * w4 + e5.y * w5 + e6.y * w6 + e7.y * w7;
    return acc;
}

__global__ __launch_bounds__(256) void hashenc_fallback(
    const float* __restrict__ x, const float* __restrict__ tables,
    float* __restrict__ out, int N)
{
    int n = blockIdx.x * blockDim.x + threadIdx.x;
    if (n >= N) return;
    float* op = out + (size_t)n * (NUM_LEVELS * LEVEL_DIM);
    #pragma unroll 4
    for (int l = 0; l < NUM_LEVELS; ++l) {
        const float* tb = tables + (size_t)l * TABLE_SIZE * LEVEL_DIM;
        v2f a = encode_point(x, tb, n, (float)(BASE_RES << l), (uint32_t)l);
        *(v2f*)(op + l * 2) = a;
    }
}

extern "C" void kernel_launch(void* const* d_in, const int* in_sizes, int n_in,
                              void* d_out, int out_size, void* d_ws, size_t ws_size,
                              hipStream_t stream) {
    const float* x      = (const float*)d_in[0];
    const float* tables = (const float*)d_in[1];
    float* out          = (float*)d_out;
    int N = in_sizes[0] / 3;

    size_t ws_needed = (size_t)NUM_LEVELS * N * LEVEL_DIM * sizeof(float);
    if (ws_size >= ws_needed) {
        float* ws = (float*)d_ws;
        gather_level_kernel<<<NUM_LEVELS * CPL, BLOCK, 0, stream>>>(x, tables, ws, N);
        int tthreads = N * 8;   // one thread per 16B output chunk
        transpose_kernel<<<(tthreads + BLOCK - 1) / BLOCK, BLOCK, 0, stream>>>(ws, out, N);
    } else {
        hashenc_fallback<<<(N + BLOCK - 1) / BLOCK, BLOCK, 0, stream>>>(x, tables, out, N);
    }
}